// Round 2
// baseline (1296.980 us; speedup 1.0000x reference)
//
#include <hip/hip_runtime.h>
#include <hip/hip_fp16.h>

constexpr int N    = 100000;
constexpr int E    = 1600000;
constexpr int FIN  = 9;
constexpr int OUTF = 6;
constexpr int G    = 1024;
constexpr int NPB  = 256;                    // nodes per bucket
constexpr int NB   = (N + NPB - 1) / NPB;    // 391 buckets
constexpr int CH   = 2048;                   // edges per chunk
constexpr int NCH  = (E + CH - 1) / CH;      // 782
constexpr int BCAP = 4864;                   // arena slots/bucket (Poisson(4096)+12 sigma)
constexpr int CBCAP= BCAP + NPB + 8;         // csc slots/bucket = 5128
constexpr int EBUF = 5888;                   // passB LDS edge stash (>= BCAP)
constexpr int ZCNT = 256 + G * 64;           // stats0+stats1+pool floats to zero

typedef _Float16 f16x8 __attribute__((ext_vector_type(8)));
typedef float    f32x4 __attribute__((ext_vector_type(4)));

__device__ __forceinline__ void atomAddF(float* p, float v) { unsafeAtomicAdd(p, v); }

// ---- init: arena cursors + zero stats/pool + zero agg9 ----
__global__ __launch_bounds__(256) void initK(int* __restrict__ cursor, float* __restrict__ zeros,
    float* __restrict__ agg9)
{
    int i = blockIdx.x * 256 + threadIdx.x;
    if (i < NB) cursor[i] = i * BCAP;
    if (i < ZCNT) zeros[i] = 0.f;
    if (i < N * FIN) agg9[i] = 0.f;
}

// ---- zero the two 64-dim f32 accumulators (after passB consumed 'bucketed' alias) ----
__global__ __launch_bounds__(256) void zeroK(f32x4* __restrict__ z)
{
    size_t i = (size_t)blockIdx.x * 256 + threadIdx.x;
    if (i < (size_t)2 * N * 64 / 4) z[i] = f32x4{0.f, 0.f, 0.f, 0.f};
}

// ---- CSC build pass 1: scatter packed edges (dst | sloc<<24, w) into fixed-stride arena,
//      bucketed by SRC (launch passes src as the 'key' array) ----
__global__ __launch_bounds__(256) void passA(const int* __restrict__ pay, const int* __restrict__ key,
    const float* __restrict__ ew, int* __restrict__ cursor, int2* __restrict__ bucketed)
{
    __shared__ int h[NB];
    __shared__ int hb[NB];
    int t = threadIdx.x;
    for (int i = t; i < NB; i += 256) h[i] = 0;
    __syncthreads();
    int base = blockIdx.x * CH;
    int myS[8], myD[8], rk[8]; float myW[8];
#pragma unroll
    for (int i = 0; i < 8; i++) {
        int e = base + i * 256 + t;
        if (e < E) {
            myS[i] = pay[e]; myD[i] = key[e]; myW[i] = ew[e];
            rk[i] = atomicAdd(&h[myD[i] >> 8], 1);
        } else myD[i] = -1;
    }
    __syncthreads();
    for (int i = t; i < NB; i += 256) hb[i] = h[i] ? atomicAdd(&cursor[i], h[i]) : 0;
    __syncthreads();
#pragma unroll
    for (int i = 0; i < 8; i++) if (myD[i] >= 0) {
        int packed = myS[i] | ((myD[i] & 255) << 24);
        bucketed[hb[myD[i] >> 8] + rk[i]] = make_int2(packed, __float_as_int(myW[i]));
    }
}

// ---- CSC build pass 2: per-bucket local CSC (LDS stash), even-aligned node regions ----
__global__ __launch_bounds__(NPB) void passB(const int* __restrict__ cursor,
    const int2* __restrict__ bucketed, int* __restrict__ ebeg, int* __restrict__ eend,
    int2* __restrict__ csr)
{
    __shared__ int2 ebuf[EBUF];
    __shared__ int cl[NPB], sa[NPB], sb[NPB], curs[NPB];
    int b = blockIdx.x, t = threadIdx.x;
    int node0 = b * NPB;
    int nnode = min(NPB, N - node0);
    int cnt = cursor[b] - b * BCAP;
    int abase = b * BCAP;
    int base = b * CBCAP;
    bool fits = (cnt <= EBUF);
    cl[t] = 0;
    __syncthreads();
    for (int e = t; e < cnt; e += NPB) {
        int2 r = bucketed[abase + e];
        if (fits) ebuf[e] = r;
        atomicAdd(&cl[((unsigned)r.x) >> 24], 1);
    }
    __syncthreads();
    int deg = cl[t];
    int pc = (deg + 1) & ~1;
    int* cur = sa; int* nxt = sb;
    cur[t] = pc;
    __syncthreads();
    for (int o = 1; o < NPB; o <<= 1) {
        int v = cur[t];
        if (t >= o) v += cur[t - o];
        nxt[t] = v;
        __syncthreads();
        int* tmp = cur; cur = nxt; nxt = tmp;
    }
    int off = cur[t] - pc;
    if (t < nnode) { ebeg[node0 + t] = base + off; eend[node0 + t] = base + off + deg; }
    curs[t] = off;
    __syncthreads();
    for (int e = t; e < cnt; e += NPB) {
        int2 r = fits ? ebuf[e] : bucketed[abase + e];
        int dl = ((unsigned)r.x) >> 24;
        int pos = base + atomicAdd(&curs[dl], 1);
        csr[pos] = make_int2(r.x & 0x00FFFFFF, r.y);
    }
    __syncthreads();
    if (t < nnode && (deg & 1)) csr[base + off + deg] = make_int2(0, 0);   // w=0 pad
    if (t < 4) csr[base + cur[NPB - 1] + t] = make_int2(0, 0);             // tail pads
}

// ---- weight prep: Wt[c][k] fp16 for layers 1,2 ----
__global__ __launch_bounds__(256) void wprep(const float* __restrict__ Wrel1, const float* __restrict__ Wroot1,
    const float* __restrict__ Wrel2, const float* __restrict__ Wroot2, __half* __restrict__ Wt)
{
    int i = blockIdx.x * 256 + threadIdx.x;      // over 2*128*64 = 16384
    int layer = i >> 13, r = i & 8191;
    int c = r >> 6, k = r & 63;
    const float* Wrel = layer ? Wrel2 : Wrel1;
    const float* Wroot = layer ? Wroot2 : Wroot1;
    float v = (c < 64) ? Wrel[k * 64 + c] : Wroot[k * 64 + (c - 64)];
    Wt[i] = __float2half(v);
}

// ---- layer-0 scatter in 9-dim: per src node, agg9[dst] += w * x[src] (fire-and-forget) ----
__global__ __launch_bounds__(256) void scatter9(const float* __restrict__ x,
    const int2* __restrict__ csc, const int* __restrict__ ebeg, const int* __restrict__ eend,
    float* __restrict__ agg9)
{
    int t = threadIdx.x, lane = t & 63;
    int e = lane / 9;                 // edge slot 0..7 (slot 7 idle)
    int f = lane - e * 9;             // feature 0..8
    bool elane = (e < 7);
    int wv = (blockIdx.x * blockDim.x + t) >> 6;
    int nw = (gridDim.x * blockDim.x) >> 6;
    for (int n = wv; n < N; n += nw) {
        int beg = ebeg[n], end = eend[n];
        if (beg >= end) continue;
        float xf = x[(size_t)n * FIN + f];          // broadcast row, read once
        int last = end - 1;
        for (int k = beg; k < end; k += 7) {
            int idx = k + e;
            int2 q = csc[min(idx, last)];
            float w = __int_as_float(q.y);
            if (elane && idx < end && w != 0.f)
                atomAddF(&agg9[(size_t)q.x * FIN + f], w * xf);
        }
    }
}

// ---- layer-0 projection (post-scatter): H0 = agg9@Wrel0 + x@Wroot0 + b0 ; BN stats ----
__global__ __launch_bounds__(256) void proj0post(const float* __restrict__ x,
    const float* __restrict__ agg9, const float* __restrict__ Wrel,
    const float* __restrict__ Wroot, const float* __restrict__ bias,
    __half* __restrict__ H0, float* __restrict__ stats)
{
    int t = threadIdx.x, j = t & 63;
    int nl = __builtin_amdgcn_readfirstlane(t >> 6);
    float wrel[FIN], wroot[FIN];
#pragma unroll
    for (int k = 0; k < FIN; k++) { wrel[k] = Wrel[k * 64 + j]; wroot[k] = Wroot[k * 64 + j]; }
    float bj = bias[j];
    float s1 = 0.f, s2 = 0.f;
    const int ntiles = N / 4;
    for (int tile = blockIdx.x; tile < ntiles; tile += gridDim.x) {
        int n = tile * 4 + nl;
        const float* xr = x + (size_t)n * FIN;
        const float* ar = agg9 + (size_t)n * FIN;
        float acc = bj;
#pragma unroll
        for (int k = 0; k < FIN; k++) {
            acc = fmaf(ar[k], wrel[k], acc);
            acc = fmaf(xr[k], wroot[k], acc);
        }
        H0[(size_t)n * 64 + j] = __float2half(acc);
        s1 += acc; s2 += acc * acc;
    }
    __shared__ float sred[256];
    sred[t] = s1; __syncthreads();
    if (t < 64) atomAddF(&stats[t], sred[t] + sred[t+64] + sred[t+128] + sred[t+192]);
    __syncthreads();
    sred[t] = s2; __syncthreads();
    if (t < 64) atomAddF(&stats[64 + t], sred[t] + sred[t+64] + sred[t+128] + sred[t+192]);
}

// ---- MFMA projection w/ fused BN+ReLU on input ----
__global__ __launch_bounds__(256) void projm(const __half* __restrict__ Hin, const __half* __restrict__ Wt,
    const float* __restrict__ bias, const float* __restrict__ stats,
    const float* __restrict__ gam, const float* __restrict__ bet,
    __half* __restrict__ P, __half* __restrict__ Hout)
{
    int t = threadIdx.x, lane = t & 63;
    int wv = blockIdx.x * 4 + (t >> 6);
    int nw = gridDim.x * 4;
    int n16 = lane & 15, quad = lane >> 4;
    constexpr float invN = 1.0f / (float)N;
    float sc[16], sh[16];
#pragma unroll
    for (int jj = 0; jj < 16; jj++) {
        int k = (jj < 8) ? (quad * 8 + jj) : (32 + quad * 8 + (jj - 8));
        float m = stats[k] * invN;
        float v = stats[64 + k] * invN - m * m;
        sc[jj] = gam[k] * rsqrtf(v + 1e-5f);
        sh[jj] = bet[k] - m * sc[jj];
    }
    f16x8 bf[8][2];
#pragma unroll
    for (int ct = 0; ct < 8; ct++)
#pragma unroll
        for (int kh = 0; kh < 2; kh++)
            bf[ct][kh] = *(const f16x8*)(Wt + (size_t)(ct * 16 + n16) * 64 + kh * 32 + quad * 8);
    float bcol[4];
#pragma unroll
    for (int i = 0; i < 4; i++) bcol[i] = bias[i * 16 + n16];
    const int NT = N / 16;
    for (int tile = wv; tile < NT; tile += nw) {
        int n0 = tile * 16;
        f16x8 r0 = *(const f16x8*)(Hin + (size_t)(n0 + n16) * 64 + quad * 8);
        f16x8 r1 = *(const f16x8*)(Hin + (size_t)(n0 + n16) * 64 + 32 + quad * 8);
        f16x8 a0, a1;
#pragma unroll
        for (int jj = 0; jj < 8; jj++) {
            a0[jj] = (_Float16)fmaxf(fmaf((float)r0[jj], sc[jj],     sh[jj]),     0.f);
            a1[jj] = (_Float16)fmaxf(fmaf((float)r1[jj], sc[jj + 8], sh[jj + 8]), 0.f);
        }
        f32x4 acc[8];
#pragma unroll
        for (int ct = 0; ct < 8; ct++) {
            f32x4 c = {0.f, 0.f, 0.f, 0.f};
            c = __builtin_amdgcn_mfma_f32_16x16x32_f16(a0, bf[ct][0], c, 0, 0, 0);
            c = __builtin_amdgcn_mfma_f32_16x16x32_f16(a1, bf[ct][1], c, 0, 0, 0);
            acc[ct] = c;
        }
#pragma unroll
        for (int ct = 0; ct < 8; ct++) {
#pragma unroll
            for (int r = 0; r < 4; r++) {
                int n = n0 + quad * 4 + r;
                if (ct < 4) P[(size_t)n * 64 + ct * 16 + n16] = __float2half(acc[ct][r]);
                else Hout[(size_t)n * 64 + (ct - 4) * 16 + n16] = __float2half(acc[ct][r] + bcol[ct - 4]);
            }
        }
    }
}

// ---- 64-dim scatter: per src node, agg[dst] += w * P[src]; all loads streaming,
//      atomics fire-and-forget (no latency stall) ----
__global__ __launch_bounds__(256) void scatterN(const __half* __restrict__ P,
    const int2* __restrict__ csc, const int* __restrict__ ebeg, const int* __restrict__ eend,
    float* __restrict__ agg)
{
    int t = threadIdx.x, lane = t & 63;
    int wv = (blockIdx.x * blockDim.x + t) >> 6;
    int nw = (gridDim.x * blockDim.x) >> 6;
    for (int n = wv; n < N; n += nw) {
        int beg = ebeg[n], end = eend[n];
        int npk = (end - beg + 1) >> 1;
        if (npk <= 0) continue;
        float p = __half2float(P[(size_t)n * 64 + lane]);
        const int4* q4 = (const int4*)csc + (beg >> 1);
        int c = npk - 1;
        // 2-deep packet rotation: prefetch k+2 while processing k
        int4 qa = q4[0];
        int4 qb = q4[min(1, c)];
        for (int k = 0; k < npk; k++) {
            int4 qn = q4[min(k + 2, c)];
            int d0 = __builtin_amdgcn_readfirstlane(qa.x);
            int w0 = __builtin_amdgcn_readfirstlane(qa.y);
            int d1 = __builtin_amdgcn_readfirstlane(qa.z);
            int w1 = __builtin_amdgcn_readfirstlane(qa.w);
            if (w0) atomAddF(&agg[(size_t)d0 * 64 + lane], __int_as_float(w0) * p);
            if (w1 && k * 2 + 1 < end - beg)
                atomAddF(&agg[(size_t)d1 * 64 + lane], __int_as_float(w1) * p);
            qa = qb; qb = qn;
        }
    }
}

// ---- finalize: r = H(root part) + agg ; EPI0: write H + BN stats ; EPI1: pool atomics ----
template<int EPI>
__global__ __launch_bounds__(256) void fin(const float* __restrict__ agg, __half* __restrict__ H,
    float* __restrict__ stats, const int* __restrict__ batch, float* __restrict__ pool)
{
    int t = threadIdx.x, j = t & 63;
    int nl = __builtin_amdgcn_readfirstlane(t >> 6);
    float s1 = 0.f, s2 = 0.f;
    const int ntiles = N / 4;
    for (int tile = blockIdx.x; tile < ntiles; tile += gridDim.x) {
        int n = tile * 4 + nl;
        float r = __half2float(H[(size_t)n * 64 + j]) + agg[(size_t)n * 64 + j];
        if constexpr (EPI == 0) {
            H[(size_t)n * 64 + j] = __float2half(r);
            s1 += r; s2 += r * r;
        } else {
            atomAddF(&pool[batch[n] * 64 + j], r);
        }
    }
    if constexpr (EPI == 0) {
        __shared__ float sred[256];
        sred[t] = s1; __syncthreads();
        if (t < 64) atomAddF(&stats[t], sred[t] + sred[t+64] + sred[t+128] + sred[t+192]);
        __syncthreads();
        sred[t] = s2; __syncthreads();
        if (t < 64) atomAddF(&stats[64 + t], sred[t] + sred[t+64] + sred[t+128] + sred[t+192]);
    }
}

// ---- head: mean-pool finalize + 2-layer MLP ----
__global__ __launch_bounds__(64) void head(const float* __restrict__ pool,
    const int* __restrict__ batch, const float* __restrict__ Wl1, const float* __restrict__ bl1,
    const float* __restrict__ Wl2, const float* __restrict__ bl2, float* __restrict__ out)
{
    int g = blockIdx.x, t = threadIdx.x;
    __shared__ float sp[64];
    __shared__ float sz[64];
    __shared__ int scnt;
    if (t == 0) {
        int lo = 0, hi = N;
        while (lo < hi) { int m = (lo + hi) >> 1; if (batch[m] < g) lo = m + 1; else hi = m; }
        int lo2 = lo, hi2 = N;
        while (lo2 < hi2) { int m = (lo2 + hi2) >> 1; if (batch[m] < g + 1) lo2 = m + 1; else hi2 = m; }
        scnt = lo2 - lo;
    }
    __syncthreads();
    float cnt = fmaxf((float)scnt, 1.0f);
    sp[t] = pool[g * 64 + t] / cnt;
    __syncthreads();
    float acc = bl1[t];
#pragma unroll
    for (int k = 0; k < 64; k++) acc = fmaf(sp[k], Wl1[k * 64 + t], acc);
    sz[t] = fmaxf(acc, 0.f);
    __syncthreads();
    if (t < OUTF) {
        float o = bl2[t];
#pragma unroll
        for (int k = 0; k < 64; k++) o = fmaf(sz[k], Wl2[k * OUTF + t], o);
        out[g * OUTF + t] = o;
    }
}

extern "C" void kernel_launch(void* const* d_in, const int* in_sizes, int n_in,
                              void* d_out, int out_size, void* d_ws, size_t ws_size,
                              hipStream_t stream)
{
    const float* x     = (const float*)d_in[0];
    const int*   ei    = (const int*)d_in[1];
    const float* ew    = (const float*)d_in[2];
    const int*   batch = (const int*)d_in[3];
    const float* Wrel0 = (const float*)d_in[4];
    const float* Wroot0= (const float*)d_in[5];
    const float* b0    = (const float*)d_in[6];
    const float* Wrel1 = (const float*)d_in[7];
    const float* Wroot1= (const float*)d_in[8];
    const float* b1    = (const float*)d_in[9];
    const float* Wrel2 = (const float*)d_in[10];
    const float* Wroot2= (const float*)d_in[11];
    const float* b2    = (const float*)d_in[12];
    const float* g0    = (const float*)d_in[13];
    const float* be0   = (const float*)d_in[14];
    const float* g1    = (const float*)d_in[15];
    const float* be1   = (const float*)d_in[16];
    const float* Wl1   = (const float*)d_in[17];
    const float* bl1   = (const float*)d_in[18];
    const float* Wl2   = (const float*)d_in[19];
    const float* bl2   = (const float*)d_in[20];
    const int* srcI = ei;
    const int* dstI = ei + E;

    __half* Ha     = (__half*)d_ws;                    // N*64 fp16
    __half* Hb     = Ha + (size_t)N * 64;              // N*64 fp16
    __half* P      = Hb + (size_t)N * 64;              // N*64 fp16
    int2*   csc    = (int2*)(P + (size_t)N * 64);      // NB*CBCAP int2 (~16 MB), by SRC
    int*    ebeg   = (int*)(csc + (size_t)NB * CBCAP); // N
    int*    eend   = ebeg + N;                         // N
    int*    cursor = eend + N;                         // NB
    float*  stats0 = (float*)(cursor + NB);            // 128 -- zero block start
    float*  stats1 = stats0 + 128;                     // 128
    float*  pool   = stats1 + 128;                     // G*64 -- zero block end
    __half* Wt1    = (__half*)(pool + G * 64);         // 128*64
    __half* Wt2    = Wt1 + 128 * 64;                   // 128*64
    float*  agg9   = (float*)(Wt2 + 128 * 64);         // N*9 f32 (3.6 MB)
    float*  aggA   = agg9 + (size_t)N * FIN;           // N*64 f32 (25.6 MB)
    float*  aggB   = aggA + (size_t)N * 64;            // N*64 f32 (25.6 MB)
    int2*   bucketed = (int2*)aggA;                    // 15.2 MB, aliases aggA (dead after passB)

    // ---- init + CSC build (bucketed arena, by SRC) ----
    initK<<<(N * FIN + 255) / 256, 256, 0, stream>>>(cursor, stats0, agg9);
    passA<<<NCH, 256, 0, stream>>>(dstI, srcI, ew, cursor, bucketed);   // payload=dst, key=src
    passB<<<NB, NPB, 0, stream>>>(cursor, bucketed, ebeg, eend, csc);
    zeroK<<<(2 * N * 64 / 4 + 255) / 256, 256, 0, stream>>>((f32x4*)aggA);  // after passB!
    wprep<<<64, 256, 0, stream>>>(Wrel1, Wroot1, Wrel2, Wroot2, Wt1);

    // ---- layer 0: 9-dim scatter then projection ----
    scatter9<<<2048, 256, 0, stream>>>(x, csc, ebeg, eend, agg9);
    proj0post<<<2048, 256, 0, stream>>>(x, agg9, Wrel0, Wroot0, b0, Ha, stats0);

    // ---- layer 1 (BN0+ReLU fused into projm input) ----
    projm<<<1024, 256, 0, stream>>>(Ha, Wt1, b1, stats0, g0, be0, P, Hb);
    scatterN<<<2048, 256, 0, stream>>>(P, csc, ebeg, eend, aggA);
    fin<0><<<2048, 256, 0, stream>>>(aggA, Hb, stats1, nullptr, nullptr);

    // ---- layer 2 + pooling (BN1+ReLU fused into projm input) ----
    projm<<<1024, 256, 0, stream>>>(Hb, Wt2, b2, stats1, g1, be1, P, Ha);
    scatterN<<<2048, 256, 0, stream>>>(P, csc, ebeg, eend, aggB);
    fin<1><<<2048, 256, 0, stream>>>(aggB, Ha, nullptr, batch, pool);

    // ---- head ----
    head<<<G, 64, 0, stream>>>(pool, batch, Wl1, bl1, Wl2, bl2, (float*)d_out);
}

// Round 3
// 546.506 us; speedup vs baseline: 2.3732x; 2.3732x over previous
//
#include <hip/hip_runtime.h>
#include <hip/hip_fp16.h>

constexpr int N    = 100000;
constexpr int E    = 1600000;
constexpr int FIN  = 9;
constexpr int OUTF = 6;
constexpr int G    = 1024;
constexpr int NPB  = 256;                    // nodes per bucket
constexpr int NB   = (N + NPB - 1) / NPB;    // 391 buckets
constexpr int CH   = 2048;                   // edges per chunk
constexpr int NCH  = (E + CH - 1) / CH;      // 782
constexpr int BCAP = 4864;                   // arena slots/bucket (Poisson(4096)+12 sigma)
constexpr int CBCAP= BCAP + NPB + 8;         // csr slots/bucket = 5128
constexpr int EBUF = 5888;                   // passB LDS edge stash (>= BCAP)
constexpr int ZCNT = 256 + G * 64;           // stats0+stats1+pool floats to zero

typedef _Float16 f16x8 __attribute__((ext_vector_type(8)));
typedef float    f32x4 __attribute__((ext_vector_type(4)));

__device__ __forceinline__ void atomAddF(float* p, float v) { unsafeAtomicAdd(p, v); }

// ---- init: arena cursors + zero stats/pool + x -> fp16 table ----
__global__ __launch_bounds__(256) void initK(int* __restrict__ cursor, float* __restrict__ zeros,
    const float* __restrict__ x, __half* __restrict__ x9)
{
    int i = blockIdx.x * 256 + threadIdx.x;
    if (i < NB) cursor[i] = i * BCAP;
    if (i < ZCNT) zeros[i] = 0.f;
    if (i < N * FIN) x9[i] = __float2half(x[i]);
}

// ---- CSR build pass 1: scatter packed edges (src | dloc<<24, w) into fixed-stride arena ----
__global__ __launch_bounds__(256) void passA(const int* __restrict__ src, const int* __restrict__ dst,
    const float* __restrict__ ew, int* __restrict__ cursor, int2* __restrict__ bucketed)
{
    __shared__ int h[NB];
    __shared__ int hb[NB];
    int t = threadIdx.x;
    for (int i = t; i < NB; i += 256) h[i] = 0;
    __syncthreads();
    int base = blockIdx.x * CH;
    int myS[8], myD[8], rk[8]; float myW[8];
#pragma unroll
    for (int i = 0; i < 8; i++) {
        int e = base + i * 256 + t;
        if (e < E) {
            myS[i] = src[e]; myD[i] = dst[e]; myW[i] = ew[e];
            rk[i] = atomicAdd(&h[myD[i] >> 8], 1);
        } else myD[i] = -1;
    }
    __syncthreads();
    for (int i = t; i < NB; i += 256) hb[i] = h[i] ? atomicAdd(&cursor[i], h[i]) : 0;
    __syncthreads();
#pragma unroll
    for (int i = 0; i < 8; i++) if (myD[i] >= 0) {
        int packed = myS[i] | ((myD[i] & 255) << 24);
        bucketed[hb[myD[i] >> 8] + rk[i]] = make_int2(packed, __float_as_int(myW[i]));
    }
}

// ---- CSR build pass 2: per-bucket local CSR (LDS stash), even-aligned node regions ----
__global__ __launch_bounds__(NPB) void passB(const int* __restrict__ cursor,
    const int2* __restrict__ bucketed, int* __restrict__ ebeg, int* __restrict__ eend,
    int2* __restrict__ csr)
{
    __shared__ int2 ebuf[EBUF];
    __shared__ int cl[NPB], sa[NPB], sb[NPB], curs[NPB];
    int b = blockIdx.x, t = threadIdx.x;
    int node0 = b * NPB;
    int nnode = min(NPB, N - node0);
    int cnt = cursor[b] - b * BCAP;
    int abase = b * BCAP;
    int base = b * CBCAP;
    bool fits = (cnt <= EBUF);
    cl[t] = 0;
    __syncthreads();
    for (int e = t; e < cnt; e += NPB) {
        int2 r = bucketed[abase + e];
        if (fits) ebuf[e] = r;
        atomicAdd(&cl[((unsigned)r.x) >> 24], 1);
    }
    __syncthreads();
    int deg = cl[t];
    int pc = (deg + 1) & ~1;
    int* cur = sa; int* nxt = sb;
    cur[t] = pc;
    __syncthreads();
    for (int o = 1; o < NPB; o <<= 1) {
        int v = cur[t];
        if (t >= o) v += cur[t - o];
        nxt[t] = v;
        __syncthreads();
        int* tmp = cur; cur = nxt; nxt = tmp;
    }
    int off = cur[t] - pc;
    if (t < nnode) { ebeg[node0 + t] = base + off; eend[node0 + t] = base + off + deg; }
    curs[t] = off;
    __syncthreads();
    for (int e = t; e < cnt; e += NPB) {
        int2 r = fits ? ebuf[e] : bucketed[abase + e];
        int dl = ((unsigned)r.x) >> 24;
        int pos = base + atomicAdd(&curs[dl], 1);
        csr[pos] = make_int2(r.x & 0x00FFFFFF, r.y);
    }
    __syncthreads();
    if (t < nnode && (deg & 1)) csr[base + off + deg] = make_int2(0, 0);   // w=0 pad
    if (t < 4) csr[base + cur[NPB - 1] + t] = make_int2(0, 0);             // tail pads
}

// ---- weight prep: Wt[c][k] fp16 for layers 1,2 ----
__global__ __launch_bounds__(256) void wprep(const float* __restrict__ Wrel1, const float* __restrict__ Wroot1,
    const float* __restrict__ Wrel2, const float* __restrict__ Wroot2, __half* __restrict__ Wt)
{
    int i = blockIdx.x * 256 + threadIdx.x;      // over 2*128*64 = 16384
    int layer = i >> 13, r = i & 8191;
    int c = r >> 6, k = r & 63;
    const float* Wrel = layer ? Wrel2 : Wrel1;
    const float* Wroot = layer ? Wroot2 : Wroot1;
    float v = (c < 64) ? Wrel[k * 64 + c] : Wroot[k * 64 + (c - 64)];
    Wt[i] = __float2half(v);
}

// ---- layer-0 gather in 9-dim, SOFTWARE-PIPELINED (2-stage csr/x9 rotation) ----
__global__ __launch_bounds__(256) void gather9(const __half* __restrict__ x9,
    const int2* __restrict__ csr, const int* __restrict__ ebeg, const int* __restrict__ eend,
    float* __restrict__ agg9)
{
    int t = threadIdx.x, lane = t & 63;
    int es = lane >> 4, fc = min(lane & 15, FIN - 1);
    int wv = (blockIdx.x * blockDim.x + t) >> 6;
    int nw = (gridDim.x * blockDim.x) >> 6;
    for (int n = wv; n < N; n += nw) {
        int beg = ebeg[n], end = eend[n];
        int last = end - 1;
        // prologue: csr for iters 0,1; x9 for iter 0
        int2 eA0 = csr[min(beg + es,      last)];
        int2 eB0 = csr[min(beg + 4 + es,  last)];
        int2 eA1 = csr[min(beg + 8 + es,  last)];
        int2 eB1 = csr[min(beg + 12 + es, last)];
        __half xA = x9[(size_t)eA0.x * FIN + fc];
        __half xB = x9[(size_t)eB0.x * FIN + fc];
        float a0 = 0.f, a1 = 0.f;
        for (int k = beg; k < end; k += 8) {
            int2 eA2 = csr[min(k + 16 + es, last)];        // csr prefetch iter+2
            int2 eB2 = csr[min(k + 20 + es, last)];
            __half nxA = x9[(size_t)eA1.x * FIN + fc];     // x9 issue for iter+1
            __half nxB = x9[(size_t)eB1.x * FIN + fc];
            float wA = (k + es     < end) ? __int_as_float(eA0.y) : 0.f;
            float wB = (k + 4 + es < end) ? __int_as_float(eB0.y) : 0.f;
            a0 = fmaf(wA, __half2float(xA), a0);           // consume iter k
            a1 = fmaf(wB, __half2float(xB), a1);
            eA0 = eA1; eB0 = eB1; eA1 = eA2; eB1 = eB2;    // rotate
            xA = nxA; xB = nxB;
        }
        float r = a0 + a1;
        r += __shfl(r, lane ^ 16, 64);
        r += __shfl(r, lane ^ 32, 64);
        if (lane < FIN) agg9[(size_t)n * FIN + lane] = r;
    }
}

// ---- layer-0 projection (post-gather): H0 = agg9@Wrel0 + x@Wroot0 + b0 ; BN stats ----
__global__ __launch_bounds__(256) void proj0post(const float* __restrict__ x,
    const float* __restrict__ agg9, const float* __restrict__ Wrel,
    const float* __restrict__ Wroot, const float* __restrict__ bias,
    __half* __restrict__ H0, float* __restrict__ stats)
{
    int t = threadIdx.x, j = t & 63;
    int nl = __builtin_amdgcn_readfirstlane(t >> 6);
    float wrel[FIN], wroot[FIN];
#pragma unroll
    for (int k = 0; k < FIN; k++) { wrel[k] = Wrel[k * 64 + j]; wroot[k] = Wroot[k * 64 + j]; }
    float bj = bias[j];
    float s1 = 0.f, s2 = 0.f;
    const int ntiles = N / 4;
    for (int tile = blockIdx.x; tile < ntiles; tile += gridDim.x) {
        int n = tile * 4 + nl;
        const float* xr = x + (size_t)n * FIN;
        const float* ar = agg9 + (size_t)n * FIN;
        float acc = bj;
#pragma unroll
        for (int k = 0; k < FIN; k++) {
            acc = fmaf(ar[k], wrel[k], acc);
            acc = fmaf(xr[k], wroot[k], acc);
        }
        H0[(size_t)n * 64 + j] = __float2half(acc);
        s1 += acc; s2 += acc * acc;
    }
    __shared__ float sred[256];
    sred[t] = s1; __syncthreads();
    if (t < 64) atomAddF(&stats[t], sred[t] + sred[t+64] + sred[t+128] + sred[t+192]);
    __syncthreads();
    sred[t] = s2; __syncthreads();
    if (t < 64) atomAddF(&stats[64 + t], sred[t] + sred[t+64] + sred[t+128] + sred[t+192]);
}

// ---- MFMA projection w/ fused BN+ReLU on input ----
__global__ __launch_bounds__(256) void projm(const __half* __restrict__ Hin, const __half* __restrict__ Wt,
    const float* __restrict__ bias, const float* __restrict__ stats,
    const float* __restrict__ gam, const float* __restrict__ bet,
    __half* __restrict__ P, __half* __restrict__ Hout)
{
    int t = threadIdx.x, lane = t & 63;
    int wv = blockIdx.x * 4 + (t >> 6);
    int nw = gridDim.x * 4;
    int n16 = lane & 15, quad = lane >> 4;
    constexpr float invN = 1.0f / (float)N;
    float sc[16], sh[16];
#pragma unroll
    for (int jj = 0; jj < 16; jj++) {
        int k = (jj < 8) ? (quad * 8 + jj) : (32 + quad * 8 + (jj - 8));
        float m = stats[k] * invN;
        float v = stats[64 + k] * invN - m * m;
        sc[jj] = gam[k] * rsqrtf(v + 1e-5f);
        sh[jj] = bet[k] - m * sc[jj];
    }
    f16x8 bf[8][2];
#pragma unroll
    for (int ct = 0; ct < 8; ct++)
#pragma unroll
        for (int kh = 0; kh < 2; kh++)
            bf[ct][kh] = *(const f16x8*)(Wt + (size_t)(ct * 16 + n16) * 64 + kh * 32 + quad * 8);
    float bcol[4];
#pragma unroll
    for (int i = 0; i < 4; i++) bcol[i] = bias[i * 16 + n16];
    const int NT = N / 16;
    for (int tile = wv; tile < NT; tile += nw) {
        int n0 = tile * 16;
        f16x8 r0 = *(const f16x8*)(Hin + (size_t)(n0 + n16) * 64 + quad * 8);
        f16x8 r1 = *(const f16x8*)(Hin + (size_t)(n0 + n16) * 64 + 32 + quad * 8);
        f16x8 a0, a1;
#pragma unroll
        for (int jj = 0; jj < 8; jj++) {
            a0[jj] = (_Float16)fmaxf(fmaf((float)r0[jj], sc[jj],     sh[jj]),     0.f);
            a1[jj] = (_Float16)fmaxf(fmaf((float)r1[jj], sc[jj + 8], sh[jj + 8]), 0.f);
        }
        f32x4 acc[8];
#pragma unroll
        for (int ct = 0; ct < 8; ct++) {
            f32x4 c = {0.f, 0.f, 0.f, 0.f};
            c = __builtin_amdgcn_mfma_f32_16x16x32_f16(a0, bf[ct][0], c, 0, 0, 0);
            c = __builtin_amdgcn_mfma_f32_16x16x32_f16(a1, bf[ct][1], c, 0, 0, 0);
            acc[ct] = c;
        }
#pragma unroll
        for (int ct = 0; ct < 8; ct++) {
#pragma unroll
            for (int r = 0; r < 4; r++) {
                int n = n0 + quad * 4 + r;
                if (ct < 4) P[(size_t)n * 64 + ct * 16 + n16] = __float2half(acc[ct][r]);
                else Hout[(size_t)n * 64 + (ct - 4) * 16 + n16] = __float2half(acc[ct][r] + bcol[ct - 4]);
            }
        }
    }
}

// ---- gather-aggregate, VECTORIZED: 16 lanes/edge, 4 features/lane (dwordx2),
//      4 edges per wave-instruction, 2-deep software pipeline ----
template<int EPI>   // 0: write H + BN stats; 1: pool atomics
__global__ __launch_bounds__(256) void gather(const __half* __restrict__ P, __half* H,
    const int2* __restrict__ csr, const int* __restrict__ ebeg, const int* __restrict__ eend,
    float* __restrict__ stats, const int* __restrict__ batch, float* __restrict__ pool)
{
    int t = threadIdx.x, lane = t & 63;
    int f4 = lane & 15;        // feature group: features 4*f4 .. 4*f4+3
    int es = lane >> 4;        // edge slot 0..3
    int wv = (blockIdx.x * blockDim.x + t) >> 6;
    int nw = (gridDim.x * blockDim.x) >> 6;
    const uint2* Pr = (const uint2*)P;         // 16 uint2 per 64-feature row
    float s1v[4] = {0.f, 0.f, 0.f, 0.f}, s2v[4] = {0.f, 0.f, 0.f, 0.f};
    for (int n = wv; n < N; n += nw) {
        int beg = ebeg[n], end = eend[n];
        float a0 = 0.f, a1 = 0.f, a2 = 0.f, a3 = 0.f;
        if (beg < end) {
            int last = end - 1;
            // prologue: csr packets for iters 0,1; P issue for iter 0
            int2 qA = csr[min(beg + es,     last)];
            int2 qB = csr[min(beg + 4 + es, last)];
            uint2 pA = Pr[(size_t)qA.x * 16 + f4];
            for (int k = beg; k < end; k += 4) {
                int2 qC = csr[min(k + 8 + es, last)];          // csr prefetch iter+2
                uint2 pB = Pr[(size_t)qB.x * 16 + f4];         // P issue for iter+1
                float w = (k + es < end) ? __int_as_float(qA.y) : 0.f;
                float2 p01 = __half22float2(__builtin_bit_cast(__half2, pA.x));
                float2 p23 = __half22float2(__builtin_bit_cast(__half2, pA.y));
                a0 = fmaf(w, p01.x, a0);
                a1 = fmaf(w, p01.y, a1);
                a2 = fmaf(w, p23.x, a2);
                a3 = fmaf(w, p23.y, a3);
                qA = qB; qB = qC; pA = pB;                     // rotate
            }
        }
        // butterfly across the 4 edge-slot groups (lane^16, lane^32)
        a0 += __shfl_xor(a0, 16, 64); a1 += __shfl_xor(a1, 16, 64);
        a2 += __shfl_xor(a2, 16, 64); a3 += __shfl_xor(a3, 16, 64);
        a0 += __shfl_xor(a0, 32, 64); a1 += __shfl_xor(a1, 32, 64);
        a2 += __shfl_xor(a2, 32, 64); a3 += __shfl_xor(a3, 32, 64);
        if (es == 0) {
            uint2 hx = ((const uint2*)H)[(size_t)n * 16 + f4];
            float2 h01 = __half22float2(__builtin_bit_cast(__half2, hx.x));
            float2 h23 = __half22float2(__builtin_bit_cast(__half2, hx.y));
            float r0 = h01.x + a0, r1 = h01.y + a1;
            float r2 = h23.x + a2, r3 = h23.y + a3;
            if constexpr (EPI == 0) {
                uint2 o;
                o.x = __builtin_bit_cast(unsigned, __floats2half2_rn(r0, r1));
                o.y = __builtin_bit_cast(unsigned, __floats2half2_rn(r2, r3));
                ((uint2*)H)[(size_t)n * 16 + f4] = o;
                s1v[0] += r0; s1v[1] += r1; s1v[2] += r2; s1v[3] += r3;
                s2v[0] += r0 * r0; s2v[1] += r1 * r1; s2v[2] += r2 * r2; s2v[3] += r3 * r3;
            } else {
                int b = batch[n];
                atomAddF(&pool[b * 64 + f4 * 4 + 0], r0);
                atomAddF(&pool[b * 64 + f4 * 4 + 1], r1);
                atomAddF(&pool[b * 64 + f4 * 4 + 2], r2);
                atomAddF(&pool[b * 64 + f4 * 4 + 3], r3);
            }
        }
    }
    if constexpr (EPI == 0) {
        __shared__ float red[4][64];
        int wi = t >> 6;
        if (es == 0) {
#pragma unroll
            for (int i = 0; i < 4; i++) red[wi][f4 * 4 + i] = s1v[i];
        }
        __syncthreads();
        if (t < 64) atomAddF(&stats[t], red[0][t] + red[1][t] + red[2][t] + red[3][t]);
        __syncthreads();
        if (es == 0) {
#pragma unroll
            for (int i = 0; i < 4; i++) red[wi][f4 * 4 + i] = s2v[i];
        }
        __syncthreads();
        if (t < 64) atomAddF(&stats[64 + t], red[0][t] + red[1][t] + red[2][t] + red[3][t]);
    }
}

// ---- head: mean-pool finalize + 2-layer MLP ----
__global__ __launch_bounds__(64) void head(const float* __restrict__ pool,
    const int* __restrict__ batch, const float* __restrict__ Wl1, const float* __restrict__ bl1,
    const float* __restrict__ Wl2, const float* __restrict__ bl2, float* __restrict__ out)
{
    int g = blockIdx.x, t = threadIdx.x;
    __shared__ float sp[64];
    __shared__ float sz[64];
    __shared__ int scnt;
    if (t == 0) {
        int lo = 0, hi = N;
        while (lo < hi) { int m = (lo + hi) >> 1; if (batch[m] < g) lo = m + 1; else hi = m; }
        int lo2 = lo, hi2 = N;
        while (lo2 < hi2) { int m = (lo2 + hi2) >> 1; if (batch[m] < g + 1) lo2 = m + 1; else hi2 = m; }
        scnt = lo2 - lo;
    }
    __syncthreads();
    float cnt = fmaxf((float)scnt, 1.0f);
    sp[t] = pool[g * 64 + t] / cnt;
    __syncthreads();
    float acc = bl1[t];
#pragma unroll
    for (int k = 0; k < 64; k++) acc = fmaf(sp[k], Wl1[k * 64 + t], acc);
    sz[t] = fmaxf(acc, 0.f);
    __syncthreads();
    if (t < OUTF) {
        float o = bl2[t];
#pragma unroll
        for (int k = 0; k < 64; k++) o = fmaf(sz[k], Wl2[k * OUTF + t], o);
        out[g * OUTF + t] = o;
    }
}

extern "C" void kernel_launch(void* const* d_in, const int* in_sizes, int n_in,
                              void* d_out, int out_size, void* d_ws, size_t ws_size,
                              hipStream_t stream)
{
    const float* x     = (const float*)d_in[0];
    const int*   ei    = (const int*)d_in[1];
    const float* ew    = (const float*)d_in[2];
    const int*   batch = (const int*)d_in[3];
    const float* Wrel0 = (const float*)d_in[4];
    const float* Wroot0= (const float*)d_in[5];
    const float* b0    = (const float*)d_in[6];
    const float* Wrel1 = (const float*)d_in[7];
    const float* Wroot1= (const float*)d_in[8];
    const float* b1    = (const float*)d_in[9];
    const float* Wrel2 = (const float*)d_in[10];
    const float* Wroot2= (const float*)d_in[11];
    const float* b2    = (const float*)d_in[12];
    const float* g0    = (const float*)d_in[13];
    const float* be0   = (const float*)d_in[14];
    const float* g1    = (const float*)d_in[15];
    const float* be1   = (const float*)d_in[16];
    const float* Wl1   = (const float*)d_in[17];
    const float* bl1   = (const float*)d_in[18];
    const float* Wl2   = (const float*)d_in[19];
    const float* bl2   = (const float*)d_in[20];
    const int* srcI = ei;
    const int* dstI = ei + E;

    __half* Ha     = (__half*)d_ws;                    // N*64 fp16
    __half* Hb     = Ha + (size_t)N * 64;              // N*64 fp16
    __half* P      = Hb + (size_t)N * 64;              // N*64 fp16
    int2*   csr    = (int2*)(P + (size_t)N * 64);      // NB*CBCAP int2 (~16 MB)
    int*    ebeg   = (int*)(csr + (size_t)NB * CBCAP); // N
    int*    eend   = ebeg + N;                         // N
    int*    cursor = eend + N;                         // NB
    float*  stats0 = (float*)(cursor + NB);            // 128 -- zero block start
    float*  stats1 = stats0 + 128;                     // 128
    float*  pool   = stats1 + 128;                     // G*64 -- zero block end
    __half* Wt1    = (__half*)(pool + G * 64);         // 128*64
    __half* Wt2    = Wt1 + 128 * 64;                   // 128*64
    float*  agg9   = (float*)(Wt2 + 128 * 64);         // N*9 f32 (3.6 MB)
    __half* x9     = (__half*)(agg9 + (size_t)N * FIN);// N*9 fp16 (1.8 MB)
    int2*   bucketed = (int2*)Ha;                      // NB*BCAP int2 = 15.2MB, aliases Ha+Hb

    // ---- init + CSR build (bucketed arena, by dst) ----
    initK<<<(N * FIN + 255) / 256, 256, 0, stream>>>(cursor, stats0, x, x9);
    passA<<<NCH, 256, 0, stream>>>(srcI, dstI, ew, cursor, bucketed);
    passB<<<NB, NPB, 0, stream>>>(cursor, bucketed, ebeg, eend, csr);
    wprep<<<64, 256, 0, stream>>>(Wrel1, Wroot1, Wrel2, Wroot2, Wt1);

    // ---- layer 0: 9-dim gather (pipelined) then projection ----
    gather9<<<2048, 256, 0, stream>>>(x9, csr, ebeg, eend, agg9);
    proj0post<<<2048, 256, 0, stream>>>(x, agg9, Wrel0, Wroot0, b0, Ha, stats0);

    // ---- layer 1 (BN0+ReLU fused into projm input) ----
    projm<<<1024, 256, 0, stream>>>(Ha, Wt1, b1, stats0, g0, be0, P, Hb);
    gather<0><<<2048, 256, 0, stream>>>(P, Hb, csr, ebeg, eend, stats1, nullptr, nullptr);

    // ---- layer 2 + pooling (BN1+ReLU fused into projm input) ----
    projm<<<1024, 256, 0, stream>>>(Hb, Wt2, b2, stats1, g1, be1, P, Ha);
    gather<1><<<2048, 256, 0, stream>>>(P, Ha, csr, ebeg, eend, nullptr, batch, pool);

    // ---- head ----
    head<<<G, 64, 0, stream>>>(pool, batch, Wl1, bl1, Wl2, bl2, (float*)d_out);
}

// Round 4
// 468.164 us; speedup vs baseline: 2.7704x; 1.1673x over previous
//
#include <hip/hip_runtime.h>
#include <hip/hip_fp16.h>

constexpr int N    = 100000;
constexpr int E    = 1600000;
constexpr int FIN  = 9;
constexpr int OUTF = 6;
constexpr int G    = 1024;
constexpr int NPB  = 256;                    // nodes per bucket
constexpr int NB   = (N + NPB - 1) / NPB;    // 391 buckets
constexpr int CH   = 2048;                   // edges per chunk
constexpr int NCH  = (E + CH - 1) / CH;      // 782
constexpr int BCAP = 4864;                   // arena slots/bucket (Poisson(4096)+12 sigma)
constexpr int CBCAP= BCAP + NPB + 8;         // csr slots/bucket = 5128
constexpr int EBUF = 5888;                   // passB LDS edge stash (>= BCAP)
constexpr int ZCNT = 256 + G * 64;           // stats0+stats1+pool floats to zero

typedef _Float16 f16x8 __attribute__((ext_vector_type(8)));
typedef float    f32x4 __attribute__((ext_vector_type(4)));

__device__ __forceinline__ void atomAddF(float* p, float v) { unsafeAtomicAdd(p, v); }

// ---- init: arena cursors + zero stats/pool + x -> fp16 table ----
__global__ __launch_bounds__(256) void initK(int* __restrict__ cursor, float* __restrict__ zeros,
    const float* __restrict__ x, __half* __restrict__ x9)
{
    int i = blockIdx.x * 256 + threadIdx.x;
    if (i < NB) cursor[i] = i * BCAP;
    if (i < ZCNT) zeros[i] = 0.f;
    if (i < N * FIN) x9[i] = __float2half(x[i]);
}

// ---- CSR build pass 1: scatter packed edges (src | dloc<<24, w) into fixed-stride arena ----
__global__ __launch_bounds__(256) void passA(const int* __restrict__ src, const int* __restrict__ dst,
    const float* __restrict__ ew, int* __restrict__ cursor, int2* __restrict__ bucketed)
{
    __shared__ int h[NB];
    __shared__ int hb[NB];
    int t = threadIdx.x;
    for (int i = t; i < NB; i += 256) h[i] = 0;
    __syncthreads();
    int base = blockIdx.x * CH;
    int myS[8], myD[8], rk[8]; float myW[8];
#pragma unroll
    for (int i = 0; i < 8; i++) {
        int e = base + i * 256 + t;
        if (e < E) {
            myS[i] = src[e]; myD[i] = dst[e]; myW[i] = ew[e];
            rk[i] = atomicAdd(&h[myD[i] >> 8], 1);
        } else myD[i] = -1;
    }
    __syncthreads();
    for (int i = t; i < NB; i += 256) hb[i] = h[i] ? atomicAdd(&cursor[i], h[i]) : 0;
    __syncthreads();
#pragma unroll
    for (int i = 0; i < 8; i++) if (myD[i] >= 0) {
        int packed = myS[i] | ((myD[i] & 255) << 24);
        bucketed[hb[myD[i] >> 8] + rk[i]] = make_int2(packed, __float_as_int(myW[i]));
    }
}

// ---- CSR build pass 2: per-bucket local CSR (LDS stash), even-aligned node regions ----
__global__ __launch_bounds__(NPB) void passB(const int* __restrict__ cursor,
    const int2* __restrict__ bucketed, int* __restrict__ ebeg, int* __restrict__ eend,
    int2* __restrict__ csr)
{
    __shared__ int2 ebuf[EBUF];
    __shared__ int cl[NPB], sa[NPB], sb[NPB], curs[NPB];
    int b = blockIdx.x, t = threadIdx.x;
    int node0 = b * NPB;
    int nnode = min(NPB, N - node0);
    int cnt = cursor[b] - b * BCAP;
    int abase = b * BCAP;
    int base = b * CBCAP;
    bool fits = (cnt <= EBUF);
    cl[t] = 0;
    __syncthreads();
    for (int e = t; e < cnt; e += NPB) {
        int2 r = bucketed[abase + e];
        if (fits) ebuf[e] = r;
        atomicAdd(&cl[((unsigned)r.x) >> 24], 1);
    }
    __syncthreads();
    int deg = cl[t];
    int pc = (deg + 1) & ~1;
    int* cur = sa; int* nxt = sb;
    cur[t] = pc;
    __syncthreads();
    for (int o = 1; o < NPB; o <<= 1) {
        int v = cur[t];
        if (t >= o) v += cur[t - o];
        nxt[t] = v;
        __syncthreads();
        int* tmp = cur; cur = nxt; nxt = tmp;
    }
    int off = cur[t] - pc;
    if (t < nnode) { ebeg[node0 + t] = base + off; eend[node0 + t] = base + off + deg; }
    curs[t] = off;
    __syncthreads();
    for (int e = t; e < cnt; e += NPB) {
        int2 r = fits ? ebuf[e] : bucketed[abase + e];
        int dl = ((unsigned)r.x) >> 24;
        int pos = base + atomicAdd(&curs[dl], 1);
        csr[pos] = make_int2(r.x & 0x00FFFFFF, r.y);
    }
    __syncthreads();
    if (t < nnode && (deg & 1)) csr[base + off + deg] = make_int2(0, 0);   // w=0 pad
    if (t < 4) csr[base + cur[NPB - 1] + t] = make_int2(0, 0);             // tail pads
}

// ---- weight prep: Wt[c][k] fp16 for layers 1,2 ----
__global__ __launch_bounds__(256) void wprep(const float* __restrict__ Wrel1, const float* __restrict__ Wroot1,
    const float* __restrict__ Wrel2, const float* __restrict__ Wroot2, __half* __restrict__ Wt)
{
    int i = blockIdx.x * 256 + threadIdx.x;      // over 2*128*64 = 16384
    int layer = i >> 13, r = i & 8191;
    int c = r >> 6, k = r & 63;
    const float* Wrel = layer ? Wrel2 : Wrel1;
    const float* Wroot = layer ? Wroot2 : Wroot1;
    float v = (c < 64) ? Wrel[k * 64 + c] : Wroot[k * 64 + (c - 64)];
    Wt[i] = __float2half(v);
}

// ---- layer-0 gather in 9-dim, SOFTWARE-PIPELINED (2-stage csr/x9 rotation) ----
__global__ __launch_bounds__(256) void gather9(const __half* __restrict__ x9,
    const int2* __restrict__ csr, const int* __restrict__ ebeg, const int* __restrict__ eend,
    float* __restrict__ agg9)
{
    int t = threadIdx.x, lane = t & 63;
    int es = lane >> 4, fc = min(lane & 15, FIN - 1);
    int wv = __builtin_amdgcn_readfirstlane((blockIdx.x * blockDim.x + t) >> 6);
    int nw = (gridDim.x * blockDim.x) >> 6;
    for (int n = wv; n < N; n += nw) {
        int beg = ebeg[n], end = eend[n];
        int last = end - 1;
        // prologue: csr for iters 0,1; x9 for iter 0
        int2 eA0 = csr[min(beg + es,      last)];
        int2 eB0 = csr[min(beg + 4 + es,  last)];
        int2 eA1 = csr[min(beg + 8 + es,  last)];
        int2 eB1 = csr[min(beg + 12 + es, last)];
        __half xA = x9[(size_t)eA0.x * FIN + fc];
        __half xB = x9[(size_t)eB0.x * FIN + fc];
        float a0 = 0.f, a1 = 0.f;
        for (int k = beg; k < end; k += 8) {
            int2 eA2 = csr[min(k + 16 + es, last)];        // csr prefetch iter+2
            int2 eB2 = csr[min(k + 20 + es, last)];
            __half nxA = x9[(size_t)eA1.x * FIN + fc];     // x9 issue for iter+1
            __half nxB = x9[(size_t)eB1.x * FIN + fc];
            float wA = (k + es     < end) ? __int_as_float(eA0.y) : 0.f;
            float wB = (k + 4 + es < end) ? __int_as_float(eB0.y) : 0.f;
            a0 = fmaf(wA, __half2float(xA), a0);           // consume iter k
            a1 = fmaf(wB, __half2float(xB), a1);
            eA0 = eA1; eB0 = eB1; eA1 = eA2; eB1 = eB2;    // rotate
            xA = nxA; xB = nxB;
        }
        float r = a0 + a1;
        r += __shfl(r, lane ^ 16, 64);
        r += __shfl(r, lane ^ 32, 64);
        if (lane < FIN) agg9[(size_t)n * FIN + lane] = r;
    }
}

// ---- layer-0 projection (post-gather): H0 = agg9@Wrel0 + x@Wroot0 + b0 ; BN stats ----
__global__ __launch_bounds__(256) void proj0post(const float* __restrict__ x,
    const float* __restrict__ agg9, const float* __restrict__ Wrel,
    const float* __restrict__ Wroot, const float* __restrict__ bias,
    __half* __restrict__ H0, float* __restrict__ stats)
{
    int t = threadIdx.x, j = t & 63;
    int nl = __builtin_amdgcn_readfirstlane(t >> 6);
    float wrel[FIN], wroot[FIN];
#pragma unroll
    for (int k = 0; k < FIN; k++) { wrel[k] = Wrel[k * 64 + j]; wroot[k] = Wroot[k * 64 + j]; }
    float bj = bias[j];
    float s1 = 0.f, s2 = 0.f;
    const int ntiles = N / 4;
    for (int tile = blockIdx.x; tile < ntiles; tile += gridDim.x) {
        int n = tile * 4 + nl;
        const float* xr = x + (size_t)n * FIN;
        const float* ar = agg9 + (size_t)n * FIN;
        float acc = bj;
#pragma unroll
        for (int k = 0; k < FIN; k++) {
            acc = fmaf(ar[k], wrel[k], acc);
            acc = fmaf(xr[k], wroot[k], acc);
        }
        H0[(size_t)n * 64 + j] = __float2half(acc);
        s1 += acc; s2 += acc * acc;
    }
    __shared__ float sred[256];
    sred[t] = s1; __syncthreads();
    if (t < 64) atomAddF(&stats[t], sred[t] + sred[t+64] + sred[t+128] + sred[t+192]);
    __syncthreads();
    sred[t] = s2; __syncthreads();
    if (t < 64) atomAddF(&stats[64 + t], sred[t] + sred[t+64] + sred[t+128] + sred[t+192]);
}

// ---- MFMA projection w/ fused BN+ReLU on input ----
__global__ __launch_bounds__(256) void projm(const __half* __restrict__ Hin, const __half* __restrict__ Wt,
    const float* __restrict__ bias, const float* __restrict__ stats,
    const float* __restrict__ gam, const float* __restrict__ bet,
    __half* __restrict__ P, __half* __restrict__ Hout)
{
    int t = threadIdx.x, lane = t & 63;
    int wv = blockIdx.x * 4 + (t >> 6);
    int nw = gridDim.x * 4;
    int n16 = lane & 15, quad = lane >> 4;
    constexpr float invN = 1.0f / (float)N;
    float sc[16], sh[16];
#pragma unroll
    for (int jj = 0; jj < 16; jj++) {
        int k = (jj < 8) ? (quad * 8 + jj) : (32 + quad * 8 + (jj - 8));
        float m = stats[k] * invN;
        float v = stats[64 + k] * invN - m * m;
        sc[jj] = gam[k] * rsqrtf(v + 1e-5f);
        sh[jj] = bet[k] - m * sc[jj];
    }
    f16x8 bf[8][2];
#pragma unroll
    for (int ct = 0; ct < 8; ct++)
#pragma unroll
        for (int kh = 0; kh < 2; kh++)
            bf[ct][kh] = *(const f16x8*)(Wt + (size_t)(ct * 16 + n16) * 64 + kh * 32 + quad * 8);
    float bcol[4];
#pragma unroll
    for (int i = 0; i < 4; i++) bcol[i] = bias[i * 16 + n16];
    const int NT = N / 16;
    for (int tile = wv; tile < NT; tile += nw) {
        int n0 = tile * 16;
        f16x8 r0 = *(const f16x8*)(Hin + (size_t)(n0 + n16) * 64 + quad * 8);
        f16x8 r1 = *(const f16x8*)(Hin + (size_t)(n0 + n16) * 64 + 32 + quad * 8);
        f16x8 a0, a1;
#pragma unroll
        for (int jj = 0; jj < 8; jj++) {
            a0[jj] = (_Float16)fmaxf(fmaf((float)r0[jj], sc[jj],     sh[jj]),     0.f);
            a1[jj] = (_Float16)fmaxf(fmaf((float)r1[jj], sc[jj + 8], sh[jj + 8]), 0.f);
        }
        f32x4 acc[8];
#pragma unroll
        for (int ct = 0; ct < 8; ct++) {
            f32x4 c = {0.f, 0.f, 0.f, 0.f};
            c = __builtin_amdgcn_mfma_f32_16x16x32_f16(a0, bf[ct][0], c, 0, 0, 0);
            c = __builtin_amdgcn_mfma_f32_16x16x32_f16(a1, bf[ct][1], c, 0, 0, 0);
            acc[ct] = c;
        }
#pragma unroll
        for (int ct = 0; ct < 8; ct++) {
#pragma unroll
            for (int r = 0; r < 4; r++) {
                int n = n0 + quad * 4 + r;
                if (ct < 4) P[(size_t)n * 64 + ct * 16 + n16] = __float2half(acc[ct][r]);
                else Hout[(size_t)n * 64 + (ct - 4) * 16 + n16] = __float2half(acc[ct][r] + bcol[ct - 4]);
            }
        }
    }
}

// ---- gather-aggregate, DEEP-PIPELINED: 3 csr packet sets (A/B/C), P issued with
//      2-iteration slack -> 16 P-loads in flight/wave; wave-uniform control scalarized ----
template<int EPI>   // 0: write H + BN stats; 1: pool atomics
__global__ __launch_bounds__(256) void gather(const __half* __restrict__ P, __half* H,
    const int2* __restrict__ csr, const int* __restrict__ ebeg, const int* __restrict__ eend,
    float* __restrict__ stats, const int* __restrict__ batch, float* __restrict__ pool)
{
    int t = threadIdx.x, lane = t & 63;
    int wv = __builtin_amdgcn_readfirstlane((blockIdx.x * blockDim.x + t) >> 6);
    int nw = (gridDim.x * blockDim.x) >> 6;
    float s1 = 0.f, s2 = 0.f;
    const int NPAIR = N / 2;
    for (int pr = wv; pr < NPAIR; pr += nw) {
        int n0 = 2 * pr, n1 = n0 + 1;
        int b0 = ebeg[n0], m0 = (eend[n0] - b0 + 1) >> 1;
        int b1 = ebeg[n1], m1 = (eend[n1] - b1 + 1) >> 1;
        const int4* q0 = (const int4*)csr + (b0 >> 1);
        const int4* q1 = (const int4*)csr + (b1 >> 1);
        int c0 = max(m0 - 1, 0), c1 = max(m1 - 1, 0);
        float x0 = __half2float(H[(size_t)n0 * 64 + lane]);
        float x1 = __half2float(H[(size_t)n1 * 64 + lane]);
        // prologue: csr packet sets A(pkts 0,1), B(2,3), C(4,5)
        int4 qaA = q0[0],          qbA = q0[min(1, c0)];
        int4 qcA = q1[0],          qdA = q1[min(1, c1)];
        int4 qaB = q0[min(2, c0)], qbB = q0[min(3, c0)];
        int4 qcB = q1[min(2, c1)], qdB = q1[min(3, c1)];
        int4 qaC = q0[min(4, c0)], qbC = q0[min(5, c0)];
        int4 qcC = q1[min(4, c1)], qdC = q1[min(5, c1)];
        // P values for set A (consume now) and set B (in flight)
        __half pa0 = P[(size_t)qaA.x * 64 + lane], pa1 = P[(size_t)qaA.z * 64 + lane];
        __half pb0 = P[(size_t)qbA.x * 64 + lane], pb1 = P[(size_t)qbA.z * 64 + lane];
        __half pc0 = P[(size_t)qcA.x * 64 + lane], pc1 = P[(size_t)qcA.z * 64 + lane];
        __half pd0 = P[(size_t)qdA.x * 64 + lane], pd1 = P[(size_t)qdA.z * 64 + lane];
        __half na0 = P[(size_t)qaB.x * 64 + lane], na1 = P[(size_t)qaB.z * 64 + lane];
        __half nb0 = P[(size_t)qbB.x * 64 + lane], nb1 = P[(size_t)qbB.z * 64 + lane];
        __half nc0 = P[(size_t)qcB.x * 64 + lane], nc1 = P[(size_t)qcB.z * 64 + lane];
        __half nd0 = P[(size_t)qdB.x * 64 + lane], nd1 = P[(size_t)qdB.z * 64 + lane];
        float a0 = 0.f, a1 = 0.f, a2 = 0.f, a3 = 0.f;
        float a4 = 0.f, a5 = 0.f, a6 = 0.f, a7 = 0.f;
        int mm = max(m0, m1);
        for (int k = 0; k < mm; k += 2) {
            // csr prefetch for packets k+6,k+7 (becomes next C)
            int4 qaD = q0[min(k + 6, c0)], qbD = q0[min(k + 7, c0)];
            int4 qcD = q1[min(k + 6, c1)], qdD = q1[min(k + 7, c1)];
            // P issue for packets k+4,k+5 via set C (2-iteration slack)
            __half ma0 = P[(size_t)qaC.x * 64 + lane], ma1 = P[(size_t)qaC.z * 64 + lane];
            __half mb0 = P[(size_t)qbC.x * 64 + lane], mb1 = P[(size_t)qbC.z * 64 + lane];
            __half mc0 = P[(size_t)qcC.x * 64 + lane], mc1 = P[(size_t)qcC.z * 64 + lane];
            __half md0 = P[(size_t)qdC.x * 64 + lane], md1 = P[(size_t)qdC.z * 64 + lane];
            // consume packets k,k+1 (set A weights x set-A P values)
            float wa = (k     < m0) ? __int_as_float(qaA.y) : 0.f;
            float wA = (k     < m0) ? __int_as_float(qaA.w) : 0.f;
            float wb = (k + 1 < m0) ? __int_as_float(qbA.y) : 0.f;
            float wB = (k + 1 < m0) ? __int_as_float(qbA.w) : 0.f;
            float wc = (k     < m1) ? __int_as_float(qcA.y) : 0.f;
            float wC = (k     < m1) ? __int_as_float(qcA.w) : 0.f;
            float wd = (k + 1 < m1) ? __int_as_float(qdA.y) : 0.f;
            float wD = (k + 1 < m1) ? __int_as_float(qdA.w) : 0.f;
            a0 = fmaf(wa, __half2float(pa0), a0); a1 = fmaf(wA, __half2float(pa1), a1);
            a2 = fmaf(wb, __half2float(pb0), a2); a3 = fmaf(wB, __half2float(pb1), a3);
            a4 = fmaf(wc, __half2float(pc0), a4); a5 = fmaf(wC, __half2float(pc1), a5);
            a6 = fmaf(wd, __half2float(pd0), a6); a7 = fmaf(wD, __half2float(pd1), a7);
            // rotate csr sets A<-B<-C<-D and P sets p<-n<-m
            qaA = qaB; qbA = qbB; qcA = qcB; qdA = qdB;
            qaB = qaC; qbB = qbC; qcB = qcC; qdB = qdC;
            qaC = qaD; qbC = qbD; qcC = qcD; qdC = qdD;
            pa0 = na0; pa1 = na1; pb0 = nb0; pb1 = nb1;
            pc0 = nc0; pc1 = nc1; pd0 = nd0; pd1 = nd1;
            na0 = ma0; na1 = ma1; nb0 = mb0; nb1 = mb1;
            nc0 = mc0; nc1 = mc1; nd0 = md0; nd1 = md1;
        }
        float r0 = x0 + ((a0 + a2) + (a1 + a3));
        float r1 = x1 + ((a4 + a6) + (a5 + a7));
        if constexpr (EPI == 0) {
            H[(size_t)n0 * 64 + lane] = __float2half(r0);
            H[(size_t)n1 * 64 + lane] = __float2half(r1);
            s1 += r0 + r1; s2 += r0 * r0 + r1 * r1;
        } else {
            atomAddF(&pool[batch[n0] * 64 + lane], r0);
            atomAddF(&pool[batch[n1] * 64 + lane], r1);
        }
    }
    if constexpr (EPI == 0) {
        __shared__ float sred[256];
        sred[t] = s1; __syncthreads();
        if (t < 64) atomAddF(&stats[t], sred[t] + sred[t+64] + sred[t+128] + sred[t+192]);
        __syncthreads();
        sred[t] = s2; __syncthreads();
        if (t < 64) atomAddF(&stats[64 + t], sred[t] + sred[t+64] + sred[t+128] + sred[t+192]);
    }
}

// ---- head: mean-pool finalize + 2-layer MLP ----
__global__ __launch_bounds__(64) void head(const float* __restrict__ pool,
    const int* __restrict__ batch, const float* __restrict__ Wl1, const float* __restrict__ bl1,
    const float* __restrict__ Wl2, const float* __restrict__ bl2, float* __restrict__ out)
{
    int g = blockIdx.x, t = threadIdx.x;
    __shared__ float sp[64];
    __shared__ float sz[64];
    __shared__ int scnt;
    if (t == 0) {
        int lo = 0, hi = N;
        while (lo < hi) { int m = (lo + hi) >> 1; if (batch[m] < g) lo = m + 1; else hi = m; }
        int lo2 = lo, hi2 = N;
        while (lo2 < hi2) { int m = (lo2 + hi2) >> 1; if (batch[m] < g + 1) lo2 = m + 1; else hi2 = m; }
        scnt = lo2 - lo;
    }
    __syncthreads();
    float cnt = fmaxf((float)scnt, 1.0f);
    sp[t] = pool[g * 64 + t] / cnt;
    __syncthreads();
    float acc = bl1[t];
#pragma unroll
    for (int k = 0; k < 64; k++) acc = fmaf(sp[k], Wl1[k * 64 + t], acc);
    sz[t] = fmaxf(acc, 0.f);
    __syncthreads();
    if (t < OUTF) {
        float o = bl2[t];
#pragma unroll
        for (int k = 0; k < 64; k++) o = fmaf(sz[k], Wl2[k * OUTF + t], o);
        out[g * OUTF + t] = o;
    }
}

extern "C" void kernel_launch(void* const* d_in, const int* in_sizes, int n_in,
                              void* d_out, int out_size, void* d_ws, size_t ws_size,
                              hipStream_t stream)
{
    const float* x     = (const float*)d_in[0];
    const int*   ei    = (const int*)d_in[1];
    const float* ew    = (const float*)d_in[2];
    const int*   batch = (const int*)d_in[3];
    const float* Wrel0 = (const float*)d_in[4];
    const float* Wroot0= (const float*)d_in[5];
    const float* b0    = (const float*)d_in[6];
    const float* Wrel1 = (const float*)d_in[7];
    const float* Wroot1= (const float*)d_in[8];
    const float* b1    = (const float*)d_in[9];
    const float* Wrel2 = (const float*)d_in[10];
    const float* Wroot2= (const float*)d_in[11];
    const float* b2    = (const float*)d_in[12];
    const float* g0    = (const float*)d_in[13];
    const float* be0   = (const float*)d_in[14];
    const float* g1    = (const float*)d_in[15];
    const float* be1   = (const float*)d_in[16];
    const float* Wl1   = (const float*)d_in[17];
    const float* bl1   = (const float*)d_in[18];
    const float* Wl2   = (const float*)d_in[19];
    const float* bl2   = (const float*)d_in[20];
    const int* srcI = ei;
    const int* dstI = ei + E;

    __half* Ha     = (__half*)d_ws;                    // N*64 fp16
    __half* Hb     = Ha + (size_t)N * 64;              // N*64 fp16
    __half* P      = Hb + (size_t)N * 64;              // N*64 fp16
    int2*   csr    = (int2*)(P + (size_t)N * 64);      // NB*CBCAP int2 (~16 MB)
    int*    ebeg   = (int*)(csr + (size_t)NB * CBCAP); // N
    int*    eend   = ebeg + N;                         // N
    int*    cursor = eend + N;                         // NB
    float*  stats0 = (float*)(cursor + NB);            // 128 -- zero block start
    float*  stats1 = stats0 + 128;                     // 128
    float*  pool   = stats1 + 128;                     // G*64 -- zero block end
    __half* Wt1    = (__half*)(pool + G * 64);         // 128*64
    __half* Wt2    = Wt1 + 128 * 64;                   // 128*64
    float*  agg9   = (float*)(Wt2 + 128 * 64);         // N*9 f32 (3.6 MB)
    __half* x9     = (__half*)(agg9 + (size_t)N * FIN);// N*9 fp16 (1.8 MB)
    int2*   bucketed = (int2*)Ha;                      // NB*BCAP int2 = 15.2MB, aliases Ha+Hb

    // ---- init + CSR build (bucketed arena, by dst) ----
    initK<<<(N * FIN + 255) / 256, 256, 0, stream>>>(cursor, stats0, x, x9);
    passA<<<NCH, 256, 0, stream>>>(srcI, dstI, ew, cursor, bucketed);
    passB<<<NB, NPB, 0, stream>>>(cursor, bucketed, ebeg, eend, csr);
    wprep<<<64, 256, 0, stream>>>(Wrel1, Wroot1, Wrel2, Wroot2, Wt1);

    // ---- layer 0: 9-dim gather (pipelined) then projection ----
    gather9<<<2048, 256, 0, stream>>>(x9, csr, ebeg, eend, agg9);
    proj0post<<<2048, 256, 0, stream>>>(x, agg9, Wrel0, Wroot0, b0, Ha, stats0);

    // ---- layer 1 (BN0+ReLU fused into projm input) ----
    projm<<<1024, 256, 0, stream>>>(Ha, Wt1, b1, stats0, g0, be0, P, Hb);
    gather<0><<<2048, 256, 0, stream>>>(P, Hb, csr, ebeg, eend, stats1, nullptr, nullptr);

    // ---- layer 2 + pooling (BN1+ReLU fused into projm input) ----
    projm<<<1024, 256, 0, stream>>>(Hb, Wt2, b2, stats1, g1, be1, P, Ha);
    gather<1><<<2048, 256, 0, stream>>>(P, Ha, csr, ebeg, eend, nullptr, batch, pool);

    // ---- head ----
    head<<<G, 64, 0, stream>>>(pool, batch, Wl1, bl1, Wl2, bl2, (float*)d_out);
}